// Round 5
// baseline (170.873 us; speedup 1.0000x reference)
//
#include <hip/hip_runtime.h>
#include <math.h>

#define CNUM 20
#define KNUM 64
#define DDIM 256
#define NHB 64

typedef __attribute__((ext_vector_type(8))) short short8;
typedef __attribute__((ext_vector_type(8))) unsigned short u16x8;
typedef __attribute__((ext_vector_type(4))) unsigned short u16x4;
typedef __attribute__((ext_vector_type(4))) float f32x4;

static __device__ __forceinline__ float shfl_xor_f(float v, int m) {
    return __shfl_xor(v, m, 64);
}

static __device__ __forceinline__ unsigned short f2bf(float f) {
    union { float f; unsigned u; } x; x.f = f;
    unsigned r = x.u + 0x7FFF + ((x.u >> 16) & 1);   // RTN-even
    return (unsigned short)(r >> 16);
}

// ---- K_A: fused setup. blocks [0,320): per-(c,k) stats + mu->bf16 (4 ck/block,
// ----      covers all 1280); [320,384): hist; [384,432): idx = -1 fill ----
__global__ void k_setup(const float* __restrict__ mu, const float* __restrict__ exp_temp,
                        const float* __restrict__ runa, const float* __restrict__ runb,
                        const float* __restrict__ med, const float* __restrict__ stdv,
                        const int* __restrict__ labels, int N, int idx_slots,
                        float* __restrict__ mu2, float* __restrict__ rtau,
                        float* __restrict__ ltau, float* __restrict__ vldf,
                        float* __restrict__ rstd, float* __restrict__ mrs,
                        unsigned short* __restrict__ mubf,
                        int* __restrict__ bc, int* __restrict__ idx)
{
    __shared__ int h[CNUM];
    const int bid = blockIdx.x, tid = threadIdx.x;
    if (bid < 320) {
        const int w = tid >> 6, lane = tid & 63;
        if (bid == 0) {
            const float r = 1.0f / stdv[tid];           // blockDim==DDIM==256
            rstd[tid] = r;
            mrs[tid] = med[tid] * r;
        }
        const int ck = bid * 4 + w;                      // covers [0, 1280)
        const float4 v = *(const float4*)(mu + (size_t)ck * DDIM + lane * 4);
        u16x4 pk;
        pk[0] = f2bf(v.x); pk[1] = f2bf(v.y); pk[2] = f2bf(v.z); pk[3] = f2bf(v.w);
        *(u16x4*)(mubf + (size_t)ck * DDIM + lane * 4) = pk;
        float s = v.x * v.x + v.y * v.y + v.z * v.z + v.w * v.w;
#pragma unroll
        for (int off = 32; off > 0; off >>= 1) s += shfl_xor_f(s, off);
        if (lane == 0) {
            mu2[ck] = s;
            const float e = exp_temp[ck];
            const float t = 100.0f / (1.0f + __expf(-0.5f * e)) + 0.01f;
            rtau[ck] = 1.0f / t;
            ltau[ck] = logf(t);
            const int c = ck >> 6;
            const float thr = runb[c] * (0.5f / (float)KNUM);
            vldf[ck] = (runa[ck] > thr) ? 1.0f : 0.0f;
        }
    } else if (bid < 384) {
        const int b2 = bid - 320;
        if (tid < CNUM) h[tid] = 0;
        __syncthreads();
        for (int i = b2 * 256 + tid; i < N; i += NHB * 256)
            atomicAdd(&h[labels[i]], 1);
        __syncthreads();
        if (tid < CNUM) bc[b2 * CNUM + tid] = h[tid];
    } else {
        for (int j = (bid - 384) * 256 + tid; j < idx_slots; j += 48 * 256)
            idx[j] = -1;
    }
}

// ---- K_B: counts, padded offsets, scatter bases, block->class map ----
__global__ void k_scan(const int* __restrict__ bc, int nb, int* __restrict__ cnt,
                       int* __restrict__ ps, int* __restrict__ sb,
                       int* __restrict__ blk2cls)
{
    const int t = threadIdx.x;
    if (t < CNUM) {
        int s = 0;
#pragma unroll 8
        for (int b = 0; b < nb; b++) s += bc[b * CNUM + t];
        cnt[t] = s;
    }
    __syncthreads();
    if (t == 0) {
        int run = 0;
        for (int c = 0; c < CNUM; c++) { ps[c] = run; run += (cnt[c] + 63) & ~63; }
        ps[CNUM] = run;
    }
    __syncthreads();
    if (t < CNUM) {
        int run = ps[t];
#pragma unroll 8
        for (int b = 0; b < nb; b++) { sb[b * CNUM + t] = run; run += bc[b * CNUM + t]; }
        const int b0 = ps[t] >> 6, b1 = ps[t + 1] >> 6;
        for (int b = b0; b < b1; b++) blk2cls[b] = t;
    }
}

// ---- K_C: scatter sample ids into class-sorted padded index array ----
__global__ void k_scatter(const int* __restrict__ labels, int N, const int* __restrict__ sb,
                          int* __restrict__ idx)
{
    __shared__ int cur[CNUM];
    const int tid = threadIdx.x;
    if (tid < CNUM) cur[tid] = sb[blockIdx.x * CNUM + tid];
    __syncthreads();
    for (int i = blockIdx.x * blockDim.x + tid; i < N; i += gridDim.x * blockDim.x) {
        const int c = labels[i];
        const int p = atomicAdd(&cur[c], 1);
        idx[p] = i;
    }
}

// ---- K_D: gather + normalize + pack bf16 into class-sorted xs; x2 per slot ----
__global__ __launch_bounds__(256, 4)
void k_norm(const float* __restrict__ data, const float* __restrict__ mrs,
            const float* __restrict__ rstd, const int* __restrict__ idx,
            const int* __restrict__ ps, unsigned short* __restrict__ xs,
            float* __restrict__ x2s)
{
    const int tid = threadIdx.x;
    const int slot = blockIdx.x * 64 + (tid >> 2);
    const int qd = tid & 3;                              // quarter (64 d)
    const int padtot = ps[CNUM];
    if (slot >= padtot) return;
    const int n = idx[slot];
    const float act = (n >= 0) ? 1.0f : 0.0f;
    const int nn = (n >= 0) ? n : 0;
    const float* __restrict__ xrow = data + (size_t)nn * DDIM + qd * 64;
    const float* __restrict__ mq = mrs + qd * 64;
    const float* __restrict__ rq = rstd + qd * 64;
    unsigned short* __restrict__ orow = xs + (size_t)slot * DDIM + qd * 64;

    // batch all 16 data loads up front (independent, contiguous 256B)
    float4 u[16];
#pragma unroll
    for (int i = 0; i < 16; ++i) u[i] = *(const float4*)(xrow + 4 * i);

    float q = 0.f;
#pragma unroll
    for (int i = 0; i < 8; ++i) {
        const float4 u0 = u[2 * i], u1 = u[2 * i + 1];
        const float4 r0 = *(const float4*)(rq + 8 * i);
        const float4 r1 = *(const float4*)(rq + 8 * i + 4);
        const float4 m0 = *(const float4*)(mq + 8 * i);
        const float4 m1 = *(const float4*)(mq + 8 * i + 4);
        float a[8];
        a[0] = act * fmaf(u0.x, r0.x, -m0.x); a[1] = act * fmaf(u0.y, r0.y, -m0.y);
        a[2] = act * fmaf(u0.z, r0.z, -m0.z); a[3] = act * fmaf(u0.w, r0.w, -m0.w);
        a[4] = act * fmaf(u1.x, r1.x, -m1.x); a[5] = act * fmaf(u1.y, r1.y, -m1.y);
        a[6] = act * fmaf(u1.z, r1.z, -m1.z); a[7] = act * fmaf(u1.w, r1.w, -m1.w);
        u16x8 pk;
#pragma unroll
        for (int j = 0; j < 8; ++j) { q = fmaf(a[j], a[j], q); pk[j] = f2bf(a[j]); }
        *(u16x8*)(orow + 8 * i) = pk;
    }
    q += shfl_xor_f(q, 1);
    q += shfl_xor_f(q, 2);
    if (qd == 0) x2s[slot] = (n >= 0) ? q : -1.0f;
}

// ---- K_E: MFMA + softmax epilogue from sorted bf16 xs ----
__global__ __launch_bounds__(256, 4)
void k_mfma(const unsigned short* __restrict__ xs, const float* __restrict__ x2s,
            const unsigned short* __restrict__ mubf,
            const float* __restrict__ mu2, const float* __restrict__ rtau,
            const float* __restrict__ ltau, const float* __restrict__ vldf,
            const int* __restrict__ ps, const int* __restrict__ blk2cls,
            float* __restrict__ wpart)
{
    const int tid = threadIdx.x, w = tid >> 6, lane = tid & 63;
    const int g = blockIdx.x;
    const int slot0 = g * 64;
    const int padtot = ps[CNUM];
    if (slot0 >= padtot) { if (lane == 0) wpart[g * 4 + w] = 0.f; return; }
    const int c = blk2cls[g];
    const int n16 = lane & 15, kg = lane >> 4;
    const int slot = slot0 + 16 * w + n16;

    const float x2 = x2s[slot];
    const float act = (x2 >= 0.f) ? 1.0f : 0.0f;
    const float q = fmaxf(x2, 0.f);

    // 8 B-frags of this lane's sample (independent 16B loads)
    const unsigned short* __restrict__ xr = xs + (size_t)slot * DDIM + 8 * kg;
    short8 xb[8];
#pragma unroll
    for (int s = 0; s < 8; ++s) xb[s] = *(const short8*)(xr + 32 * s);

    // MFMA with A-frag (mu) prefetch one K-step ahead
    const unsigned short* __restrict__ mbase =
        mubf + ((size_t)c * KNUM + n16) * DDIM + 8 * kg;
    short8 afn[4];
#pragma unroll
    for (int f = 0; f < 4; ++f) afn[f] = *(const short8*)(mbase + f * 16 * DDIM);
    f32x4 acc[4] = {};
#pragma unroll
    for (int s = 0; s < 8; ++s) {
        short8 af[4];
#pragma unroll
        for (int f = 0; f < 4; ++f) af[f] = afn[f];
        if (s < 7) {
#pragma unroll
            for (int f = 0; f < 4; ++f)
                afn[f] = *(const short8*)(mbase + f * 16 * DDIM + 32 * (s + 1));
        }
#pragma unroll
        for (int f = 0; f < 4; ++f)
            acc[f] = __builtin_amdgcn_mfma_f32_16x16x32_bf16(af[f], xb[s], acc[f], 0, 0, 0);
    }

    // epilogue: lane holds 16 k-values (k = 16f + 4kg + r) of its sample
    const int ckb = c * KNUM;
    float simv[16], lpv[16];
    float mxv = -3.4e38f;
#pragma unroll
    for (int f = 0; f < 4; ++f) {
        const int kb = ckb + 16 * f + 4 * kg;
        const float4 m2v = *(const float4*)(mu2 + kb);
        const float4 rtv = *(const float4*)(rtau + kb);
        const float4 ltv = *(const float4*)(ltau + kb);
        const float4 vlv = *(const float4*)(vldf + kb);
#pragma unroll
        for (int r = 0; r < 4; ++r) {
            const float m2 = (&m2v.x)[r];
            const float d2 = fmaxf(fmaf(-2.0f, acc[f][r], q + m2), 0.f);
            const float dist = -6.25f * sqrtf(d2);       // 100/sqrt(256)
            const float sim = ((&vlv.x)[r] > 0.5f) ? dist : -1.0e12f;
            simv[4 * f + r] = sim;
            lpv[4 * f + r] = fmaf(sim, (&rtv.x)[r], -(&ltv.x)[r]);
            mxv = fmaxf(mxv, 0.5f * sim);
        }
    }
    mxv = fmaxf(mxv, shfl_xor_f(mxv, 16));
    mxv = fmaxf(mxv, shfl_xor_f(mxv, 32));
    float se = 0.f, sl = 0.f;
#pragma unroll
    for (int i = 0; i < 16; ++i) {
        const float e = __expf(fmaf(0.5f, simv[i], -mxv));
        se += e;
        sl = fmaf(e, lpv[i], sl);
    }
    se += shfl_xor_f(se, 16); se += shfl_xor_f(se, 32);
    sl += shfl_xor_f(sl, 16); sl += shfl_xor_f(sl, 32);
    float res = (kg == 0 && act > 0.f) ? (-sl / se) : 0.f;
    res += shfl_xor_f(res, 1);
    res += shfl_xor_f(res, 2);
    res += shfl_xor_f(res, 4);
    res += shfl_xor_f(res, 8);
    if (lane == 0) wpart[g * 4 + w] = res;
}

// ---- fallback: R3 single-pass main (used only if ws too small for xs) ----
__global__ __launch_bounds__(256, 4)
void k_main_fb(const float* __restrict__ data, const unsigned short* __restrict__ mubf,
               const float* __restrict__ mrs, const float* __restrict__ rstd,
               const float* __restrict__ mu2, const float* __restrict__ rtau,
               const float* __restrict__ ltau, const float* __restrict__ vldf,
               const int* __restrict__ idx, const int* __restrict__ ps,
               const int* __restrict__ blk2cls, float* __restrict__ wpart)
{
    const int tid = threadIdx.x, w = tid >> 6, lane = tid & 63;
    const int g = blockIdx.x;
    const int slot0 = g * 64;
    const int padtot = ps[CNUM];
    if (slot0 >= padtot) { if (lane == 0) wpart[g * 4 + w] = 0.f; return; }
    const int c = blk2cls[g];
    const int n16 = lane & 15, kg = lane >> 4;
    const int n = idx[slot0 + 16 * w + n16];
    const float act = (n >= 0) ? 1.0f : 0.0f;
    const int nn = (n >= 0) ? n : 0;
    const float* __restrict__ xrow = data + (size_t)nn * DDIM;
    short8 xb[8];
    float q = 0.f;
#pragma unroll
    for (int s = 0; s < 8; ++s) {
        const int d = 32 * s + 8 * kg;
        const float4 u0 = *(const float4*)(xrow + d);
        const float4 u1 = *(const float4*)(xrow + d + 4);
        const float4 r0 = *(const float4*)(rstd + d);
        const float4 r1 = *(const float4*)(rstd + d + 4);
        const float4 m0 = *(const float4*)(mrs + d);
        const float4 m1 = *(const float4*)(mrs + d + 4);
        float a[8];
        a[0] = act * fmaf(u0.x, r0.x, -m0.x); a[1] = act * fmaf(u0.y, r0.y, -m0.y);
        a[2] = act * fmaf(u0.z, r0.z, -m0.z); a[3] = act * fmaf(u0.w, r0.w, -m0.w);
        a[4] = act * fmaf(u1.x, r1.x, -m1.x); a[5] = act * fmaf(u1.y, r1.y, -m1.y);
        a[6] = act * fmaf(u1.z, r1.z, -m1.z); a[7] = act * fmaf(u1.w, r1.w, -m1.w);
        short8 pk;
#pragma unroll
        for (int j = 0; j < 8; ++j) { q = fmaf(a[j], a[j], q); pk[j] = (short)f2bf(a[j]); }
        xb[s] = pk;
    }
    q += shfl_xor_f(q, 16);
    q += shfl_xor_f(q, 32);
    f32x4 acc[4] = {};
    const unsigned short* __restrict__ mbase = mubf + (size_t)c * KNUM * DDIM;
#pragma unroll
    for (int s = 0; s < 8; ++s) {
        short8 af[4];
#pragma unroll
        for (int f = 0; f < 4; ++f)
            af[f] = *(const short8*)(mbase + (16 * f + n16) * DDIM + 32 * s + 8 * kg);
#pragma unroll
        for (int f = 0; f < 4; ++f)
            acc[f] = __builtin_amdgcn_mfma_f32_16x16x32_bf16(af[f], xb[s], acc[f], 0, 0, 0);
    }
    const int ckb = c * KNUM;
    float simv[16], lpv[16];
    float mxv = -3.4e38f;
#pragma unroll
    for (int f = 0; f < 4; ++f) {
        const int kb = ckb + 16 * f + 4 * kg;
        const float4 m2v = *(const float4*)(mu2 + kb);
        const float4 rtv = *(const float4*)(rtau + kb);
        const float4 ltv = *(const float4*)(ltau + kb);
        const float4 vlv = *(const float4*)(vldf + kb);
#pragma unroll
        for (int r = 0; r < 4; ++r) {
            const float m2 = (&m2v.x)[r];
            const float d2 = fmaxf(fmaf(-2.0f, acc[f][r], q + m2), 0.f);
            const float dist = -6.25f * sqrtf(d2);
            const float sim = ((&vlv.x)[r] > 0.5f) ? dist : -1.0e12f;
            simv[4 * f + r] = sim;
            lpv[4 * f + r] = fmaf(sim, (&rtv.x)[r], -(&ltv.x)[r]);
            mxv = fmaxf(mxv, 0.5f * sim);
        }
    }
    mxv = fmaxf(mxv, shfl_xor_f(mxv, 16));
    mxv = fmaxf(mxv, shfl_xor_f(mxv, 32));
    float se = 0.f, sl = 0.f;
#pragma unroll
    for (int i = 0; i < 16; ++i) {
        const float e = __expf(fmaf(0.5f, simv[i], -mxv));
        se += e;
        sl = fmaf(e, lpv[i], sl);
    }
    se += shfl_xor_f(se, 16); se += shfl_xor_f(se, 32);
    sl += shfl_xor_f(sl, 16); sl += shfl_xor_f(sl, 32);
    float res = (kg == 0 && n >= 0) ? (-sl / se) : 0.f;
    res += shfl_xor_f(res, 1);
    res += shfl_xor_f(res, 2);
    res += shfl_xor_f(res, 4);
    res += shfl_xor_f(res, 8);
    if (lane == 0) wpart[g * 4 + w] = res;
}

// ---- K_F: deterministic per-class reduce -> loss ----
__global__ void k_final(const float* __restrict__ wpart, const int* __restrict__ ps,
                        const int* __restrict__ cnt, float* __restrict__ out)
{
    __shared__ float seg[CNUM];
    const int t = threadIdx.x;
    if (t < CNUM) {
        float s = 0.f;
        const int b0 = ps[t] >> 6, b1 = ps[t + 1] >> 6;
        for (int b = b0; b < b1; b++) {
            const float4 v = *(const float4*)(wpart + 4 * b);
            s += ((v.x + v.y) + (v.z + v.w));
        }
        seg[t] = s;
    }
    __syncthreads();
    if (t == 0) {
        float loss = 0.f;
        for (int c = 0; c < CNUM; c++) {
            const float cc = (float)cnt[c];
            if (cc > 0.f) loss += seg[c] / fmaxf(cc, 1.0f);
        }
        out[0] = loss;
    }
}

extern "C" void kernel_launch(void* const* d_in, const int* in_sizes, int n_in,
                              void* d_out, int out_size, void* d_ws, size_t ws_size,
                              hipStream_t stream)
{
    const float* data     = (const float*)d_in[0];
    const int*   labels   = (const int*)d_in[1];
    const float* mu       = (const float*)d_in[2];
    const float* exp_temp = (const float*)d_in[3];
    const float* med      = (const float*)d_in[4];
    const float* stdv     = (const float*)d_in[5];
    const float* runa     = (const float*)d_in[6];
    const float* runb     = (const float*)d_in[7];
    float* out = (float*)d_out;
    const int N = in_sizes[0] / DDIM;
    const int idx_slots = N + CNUM * 64;
    const int NB = (idx_slots + 63) / 64;

    char* w = (char*)d_ws;
    float* mu2  = (float*)w; w += (size_t)CNUM * KNUM * 4;
    float* rtau = (float*)w; w += (size_t)CNUM * KNUM * 4;
    float* ltau = (float*)w; w += (size_t)CNUM * KNUM * 4;
    float* vldf = (float*)w; w += (size_t)CNUM * KNUM * 4;
    float* rstd = (float*)w; w += (size_t)DDIM * 4;
    float* mrs  = (float*)w; w += (size_t)DDIM * 4;
    unsigned short* mubf = (unsigned short*)w; w += (size_t)CNUM * KNUM * DDIM * 2;
    int* bc  = (int*)w; w += (size_t)NHB * CNUM * 4;
    int* sb  = (int*)w; w += (size_t)NHB * CNUM * 4;
    int* cnt = (int*)w; w += 64 * 4;
    int* ps  = (int*)w; w += 64 * 4;
    int* idx = (int*)w; w += (size_t)idx_slots * 4;
    int* blk2cls = (int*)w; w += (size_t)NB * 4;
    float* wp = (float*)w; w += (size_t)NB * 4 * 4;
    float* x2s = (float*)w; w += (size_t)idx_slots * 4;
    unsigned short* xs = (unsigned short*)w; w += (size_t)idx_slots * DDIM * 2;
    const size_t need = (size_t)(w - (char*)d_ws);

    k_setup<<<dim3(432), dim3(256), 0, stream>>>(
        mu, exp_temp, runa, runb, med, stdv, labels, N, idx_slots,
        mu2, rtau, ltau, vldf, rstd, mrs, mubf, bc, idx);
    k_scan<<<dim3(1), dim3(64), 0, stream>>>(bc, NHB, cnt, ps, sb, blk2cls);
    k_scatter<<<dim3(NHB), dim3(256), 0, stream>>>(labels, N, sb, idx);
    if (ws_size >= need) {
        k_norm<<<dim3(NB), dim3(256), 0, stream>>>(data, mrs, rstd, idx, ps, xs, x2s);
        k_mfma<<<dim3(NB), dim3(256), 0, stream>>>(
            xs, x2s, mubf, mu2, rtau, ltau, vldf, ps, blk2cls, wp);
    } else {
        k_main_fb<<<dim3(NB), dim3(256), 0, stream>>>(
            data, mubf, mrs, rstd, mu2, rtau, ltau, vldf, idx, ps, blk2cls, wp);
    }
    k_final<<<dim3(1), dim3(32), 0, stream>>>(wp, ps, cnt, out);
}

// Round 6
// 120.017 us; speedup vs baseline: 1.4237x; 1.4237x over previous
//
#include <hip/hip_runtime.h>
#include <math.h>

#define CNUM 20
#define KNUM 64
#define DDIM 256
#define NHB 64

typedef __attribute__((ext_vector_type(8))) short short8;
typedef __attribute__((ext_vector_type(4))) unsigned short u16x4;
typedef __attribute__((ext_vector_type(4))) float f32x4;

static __device__ __forceinline__ float shfl_xor_f(float v, int m) {
    return __shfl_xor(v, m, 64);
}

static __device__ __forceinline__ unsigned short f2bf(float f) {
    union { float f; unsigned u; } x; x.f = f;
    unsigned r = x.u + 0x7FFF + ((x.u >> 16) & 1);   // RTN-even
    return (unsigned short)(r >> 16);
}

static __device__ __forceinline__ float bf2f(unsigned short h) {
    union { unsigned u; float f; } x; x.u = ((unsigned)h) << 16;
    return x.f;
}

// ---- K_A: fused setup. blocks [0,320): per-(c,k) stats + mu->bf16 (4 ck/block);
// ----      [320,384): label histogram ----
__global__ void k_setup(const float* __restrict__ mu, const float* __restrict__ exp_temp,
                        const float* __restrict__ runa, const float* __restrict__ runb,
                        const float* __restrict__ med, const float* __restrict__ stdv,
                        const int* __restrict__ labels, int N,
                        float* __restrict__ mu2, float* __restrict__ rtau,
                        float* __restrict__ ltau, float* __restrict__ vldf,
                        float* __restrict__ rstd, float* __restrict__ mrs,
                        unsigned short* __restrict__ mubf, int* __restrict__ bc)
{
    __shared__ int h[CNUM];
    const int bid = blockIdx.x, tid = threadIdx.x;
    if (bid < 320) {
        const int w = tid >> 6, lane = tid & 63;
        if (bid == 0) {
            const float r = 1.0f / stdv[tid];           // blockDim==DDIM==256
            rstd[tid] = r;
            mrs[tid] = med[tid] * r;
        }
        const int ck = bid * 4 + w;                      // covers [0, 1280)
        const float4 v = *(const float4*)(mu + (size_t)ck * DDIM + lane * 4);
        u16x4 pk;
        pk[0] = f2bf(v.x); pk[1] = f2bf(v.y); pk[2] = f2bf(v.z); pk[3] = f2bf(v.w);
        *(u16x4*)(mubf + (size_t)ck * DDIM + lane * 4) = pk;
        float s = v.x * v.x + v.y * v.y + v.z * v.z + v.w * v.w;
#pragma unroll
        for (int off = 32; off > 0; off >>= 1) s += shfl_xor_f(s, off);
        if (lane == 0) {
            mu2[ck] = s;
            const float e = exp_temp[ck];
            const float t = 100.0f / (1.0f + __expf(-0.5f * e)) + 0.01f;
            rtau[ck] = 1.0f / t;
            ltau[ck] = logf(t);
            const int c = ck >> 6;
            const float thr = runb[c] * (0.5f / (float)KNUM);
            vldf[ck] = (runa[ck] > thr) ? 1.0f : 0.0f;
        }
    } else {
        const int b2 = bid - 320;
        if (tid < CNUM) h[tid] = 0;
        __syncthreads();
        for (int i = b2 * 256 + tid; i < N; i += NHB * 256)
            atomicAdd(&h[labels[i]], 1);
        __syncthreads();
        if (tid < CNUM) bc[b2 * CNUM + tid] = h[tid];
    }
}

// ---- K_B: counts, padded offsets, scatter bases, block->class map ----
__global__ void k_scan(const int* __restrict__ bc, int nb, int* __restrict__ cnt,
                       int* __restrict__ ps, int* __restrict__ sb,
                       int* __restrict__ blk2cls)
{
    const int t = threadIdx.x;
    if (t < CNUM) {
        int s = 0;
#pragma unroll 8
        for (int b = 0; b < nb; b++) s += bc[b * CNUM + t];
        cnt[t] = s;
    }
    __syncthreads();
    if (t == 0) {
        int run = 0;
        for (int c = 0; c < CNUM; c++) { ps[c] = run; run += (cnt[c] + 63) & ~63; }
        ps[CNUM] = run;
    }
    __syncthreads();
    if (t < CNUM) {
        int run = ps[t];
#pragma unroll 8
        for (int b = 0; b < nb; b++) { sb[b * CNUM + t] = run; run += bc[b * CNUM + t]; }
        const int b0 = ps[t] >> 6, b1 = ps[t + 1] >> 6;
        for (int b = b0; b < b1; b++) blk2cls[b] = t;
    }
}

// ---- K_C: scatter sample ids into class-sorted padded index array ----
__global__ void k_scatter(const int* __restrict__ labels, int N, const int* __restrict__ sb,
                          int* __restrict__ idx)
{
    __shared__ int cur[CNUM];
    const int tid = threadIdx.x;
    if (tid < CNUM) cur[tid] = sb[blockIdx.x * CNUM + tid];
    __syncthreads();
    for (int i = blockIdx.x * blockDim.x + tid; i < N; i += gridDim.x * blockDim.x) {
        const int c = labels[i];
        const int p = atomicAdd(&cur[c], 1);
        idx[p] = i;
    }
}

// ---- K_D: main — cooperative gather -> LDS bf16 tile -> MFMA -> softmax ----
__global__ __launch_bounds__(256, 3)
void k_main(const float* __restrict__ data, const unsigned short* __restrict__ mubf,
            const float* __restrict__ mrs, const float* __restrict__ rstd,
            const float* __restrict__ mu2, const float* __restrict__ rtau,
            const float* __restrict__ ltau, const float* __restrict__ vldf,
            const int* __restrict__ idx, const int* __restrict__ ps,
            const int* __restrict__ cnt, const int* __restrict__ blk2cls,
            float* __restrict__ wpart)
{
    __shared__ __align__(16) unsigned char Xs[64 * 512];   // [row][256 bf16], 16B-XOR swizzled
    const int tid = threadIdx.x, w = tid >> 6, lane = tid & 63;
    const int g = blockIdx.x;
    const int slot0 = g * 64;
    const int padtot = ps[CNUM];
    if (slot0 >= padtot) { if (lane == 0) wpart[g * 4 + w] = 0.f; return; }
    const int c = blk2cls[g];
    const int realend = ps[c] + cnt[c];

    // ---- stage: wave w loads rows [16w,16w+16), 1KB coalesced per row ----
    {
        const float4 m4 = *(const float4*)(mrs + 4 * lane);
        const float4 r4 = *(const float4*)(rstd + 4 * lane);
#pragma unroll
        for (int r = 0; r < 16; ++r) {
            const int row = 16 * w + r;
            const int slot = slot0 + row;
            if (slot < realend) {                        // wave-uniform guard
                const int n = idx[slot];                 // wave-uniform scalar load
                const float4 u = *(const float4*)(data + (size_t)n * DDIM + 4 * lane);
                u16x4 pk;
                pk[0] = f2bf(fmaf(u.x, r4.x, -m4.x));
                pk[1] = f2bf(fmaf(u.y, r4.y, -m4.y));
                pk[2] = f2bf(fmaf(u.z, r4.z, -m4.z));
                pk[3] = f2bf(fmaf(u.w, r4.w, -m4.w));
                *(u16x4*)(Xs + row * 512 + ((8 * lane) ^ ((row & 7) << 4))) = pk;
            }
        }
    }
    __syncthreads();

    // ---- MFMA: A = mu rows (k), B = X rows (samples); C[k][sample] ----
    const int n16 = lane & 15, kg = lane >> 4;
    const int brow = 16 * w + n16;                       // this lane's sample row
    const unsigned char* __restrict__ xr = Xs + brow * 512;
    const int bswz = (n16 & 7) << 4;
    short8 xb[8];
#pragma unroll
    for (int s = 0; s < 8; ++s)
        xb[s] = *(const short8*)(xr + ((64 * s + 16 * kg) ^ bswz));

    const unsigned short* __restrict__ mbase =
        mubf + ((size_t)c * KNUM + n16) * DDIM + 8 * kg;
    short8 afn[4];
#pragma unroll
    for (int f = 0; f < 4; ++f) afn[f] = *(const short8*)(mbase + f * 16 * DDIM);
    f32x4 acc[4] = {};
#pragma unroll
    for (int s = 0; s < 8; ++s) {
        short8 af[4];
#pragma unroll
        for (int f = 0; f < 4; ++f) af[f] = afn[f];
        if (s < 7) {
#pragma unroll
            for (int f = 0; f < 4; ++f)
                afn[f] = *(const short8*)(mbase + f * 16 * DDIM + 32 * (s + 1));
        }
#pragma unroll
        for (int f = 0; f < 4; ++f)
            acc[f] = __builtin_amdgcn_mfma_f32_16x16x32_bf16(af[f], xb[s], acc[f], 0, 0, 0);
    }

    // ---- |x|^2 from the bf16 fragments (consistent with the dot) ----
    float q = 0.f;
#pragma unroll
    for (int s = 0; s < 8; ++s)
#pragma unroll
        for (int j = 0; j < 8; ++j) {
            const float f = bf2f((unsigned short)xb[s][j]);
            q = fmaf(f, f, q);
        }
    q += shfl_xor_f(q, 16);
    q += shfl_xor_f(q, 32);

    // ---- epilogue: lane holds 16 k-values (k = 16f + 4kg + r) of its sample ----
    const int ckb = c * KNUM;
    float simv[16], lpv[16];
    float mxv = -3.4e38f;
#pragma unroll
    for (int f = 0; f < 4; ++f) {
        const int kb = ckb + 16 * f + 4 * kg;
        const float4 m2v = *(const float4*)(mu2 + kb);
        const float4 rtv = *(const float4*)(rtau + kb);
        const float4 ltv = *(const float4*)(ltau + kb);
        const float4 vlv = *(const float4*)(vldf + kb);
#pragma unroll
        for (int r = 0; r < 4; ++r) {
            const float m2 = (&m2v.x)[r];
            const float d2 = fmaxf(fmaf(-2.0f, acc[f][r], q + m2), 0.f);
            const float dist = -6.25f * sqrtf(d2);       // 100/sqrt(256)
            const float sim = ((&vlv.x)[r] > 0.5f) ? dist : -1.0e12f;
            simv[4 * f + r] = sim;
            lpv[4 * f + r] = fmaf(sim, (&rtv.x)[r], -(&ltv.x)[r]);
            mxv = fmaxf(mxv, 0.5f * sim);
        }
    }
    mxv = fmaxf(mxv, shfl_xor_f(mxv, 16));
    mxv = fmaxf(mxv, shfl_xor_f(mxv, 32));
    float se = 0.f, sl = 0.f;
#pragma unroll
    for (int i = 0; i < 16; ++i) {
        const float e = __expf(fmaf(0.5f, simv[i], -mxv));
        se += e;
        sl = fmaf(e, lpv[i], sl);
    }
    se += shfl_xor_f(se, 16); se += shfl_xor_f(se, 32);
    sl += shfl_xor_f(sl, 16); sl += shfl_xor_f(sl, 32);
    const int slot = slot0 + brow;
    float res = (kg == 0 && slot < realend) ? (-sl / se) : 0.f;
    res += shfl_xor_f(res, 1);
    res += shfl_xor_f(res, 2);
    res += shfl_xor_f(res, 4);
    res += shfl_xor_f(res, 8);
    if (lane == 0) wpart[g * 4 + w] = res;
}

// ---- K_E: deterministic per-class reduce -> loss ----
__global__ void k_final(const float* __restrict__ wpart, const int* __restrict__ ps,
                        const int* __restrict__ cnt, float* __restrict__ out)
{
    __shared__ float seg[CNUM];
    const int t = threadIdx.x;
    if (t < CNUM) {
        float s = 0.f;
        const int b0 = ps[t] >> 6, b1 = ps[t + 1] >> 6;
        for (int b = b0; b < b1; b++) {
            const float4 v = *(const float4*)(wpart + 4 * b);
            s += ((v.x + v.y) + (v.z + v.w));
        }
        seg[t] = s;
    }
    __syncthreads();
    if (t == 0) {
        float loss = 0.f;
        for (int c = 0; c < CNUM; c++) {
            const float cc = (float)cnt[c];
            if (cc > 0.f) loss += seg[c] / fmaxf(cc, 1.0f);
        }
        out[0] = loss;
    }
}

extern "C" void kernel_launch(void* const* d_in, const int* in_sizes, int n_in,
                              void* d_out, int out_size, void* d_ws, size_t ws_size,
                              hipStream_t stream)
{
    const float* data     = (const float*)d_in[0];
    const int*   labels   = (const int*)d_in[1];
    const float* mu       = (const float*)d_in[2];
    const float* exp_temp = (const float*)d_in[3];
    const float* med      = (const float*)d_in[4];
    const float* stdv     = (const float*)d_in[5];
    const float* runa     = (const float*)d_in[6];
    const float* runb     = (const float*)d_in[7];
    float* out = (float*)d_out;
    const int N = in_sizes[0] / DDIM;
    const int idx_slots = N + CNUM * 64;
    const int NB = (idx_slots + 63) / 64;

    char* w = (char*)d_ws;
    float* mu2  = (float*)w; w += (size_t)CNUM * KNUM * 4;
    float* rtau = (float*)w; w += (size_t)CNUM * KNUM * 4;
    float* ltau = (float*)w; w += (size_t)CNUM * KNUM * 4;
    float* vldf = (float*)w; w += (size_t)CNUM * KNUM * 4;
    float* rstd = (float*)w; w += (size_t)DDIM * 4;
    float* mrs  = (float*)w; w += (size_t)DDIM * 4;
    unsigned short* mubf = (unsigned short*)w; w += (size_t)CNUM * KNUM * DDIM * 2;
    int* bc  = (int*)w; w += (size_t)NHB * CNUM * 4;
    int* sb  = (int*)w; w += (size_t)NHB * CNUM * 4;
    int* cnt = (int*)w; w += 64 * 4;
    int* ps  = (int*)w; w += 64 * 4;
    int* idx = (int*)w; w += (size_t)idx_slots * 4;
    int* blk2cls = (int*)w; w += (size_t)NB * 4;
    float* wp = (float*)w; w += (size_t)NB * 4 * 4;

    k_setup<<<dim3(384), dim3(256), 0, stream>>>(
        mu, exp_temp, runa, runb, med, stdv, labels, N,
        mu2, rtau, ltau, vldf, rstd, mrs, mubf, bc);
    k_scan<<<dim3(1), dim3(64), 0, stream>>>(bc, NHB, cnt, ps, sb, blk2cls);
    k_scatter<<<dim3(NHB), dim3(256), 0, stream>>>(labels, N, sb, idx);
    k_main<<<dim3(NB), dim3(256), 0, stream>>>(
        data, mubf, mrs, rstd, mu2, rtau, ltau, vldf, idx, ps, cnt, blk2cls, wp);
    k_final<<<dim3(1), dim3(32), 0, stream>>>(wp, ps, cnt, out);
}

// Round 7
// 114.195 us; speedup vs baseline: 1.4963x; 1.0510x over previous
//
#include <hip/hip_runtime.h>
#include <hip/hip_bf16.h>
#include <math.h>

#define CNUM 20
#define KNUM 64
#define DDIM 256
#define NHB 64

typedef __attribute__((ext_vector_type(8))) short short8;
typedef __attribute__((ext_vector_type(4))) unsigned short u16x4;
typedef __attribute__((ext_vector_type(4))) float f32x4;

static __device__ __forceinline__ float shfl_xor_f(float v, int m) {
    return __shfl_xor(v, m, 64);
}

static __device__ __forceinline__ unsigned short f2bf(float f) {
    union { float f; unsigned u; } x; x.f = f;
    unsigned r = x.u + 0x7FFF + ((x.u >> 16) & 1);   // RTN-even
    return (unsigned short)(r >> 16);
}

// ---- K_A: fused setup. blocks [0,320): per-(c,k) stats + mu->bf16 (4 ck/block);
// ----      [320,384): label histogram ----
__global__ void k_setup(const float* __restrict__ mu, const float* __restrict__ exp_temp,
                        const float* __restrict__ runa, const float* __restrict__ runb,
                        const float* __restrict__ med, const float* __restrict__ stdv,
                        const int* __restrict__ labels, int N,
                        float* __restrict__ mu2, float* __restrict__ rtau,
                        float* __restrict__ ltau, float* __restrict__ vldf,
                        float* __restrict__ rstd, float* __restrict__ mrs,
                        unsigned short* __restrict__ mubf, int* __restrict__ bc)
{
    __shared__ int h[CNUM];
    const int bid = blockIdx.x, tid = threadIdx.x;
    if (bid < 320) {
        const int w = tid >> 6, lane = tid & 63;
        if (bid == 0) {
            const float r = 1.0f / stdv[tid];           // blockDim==DDIM==256
            rstd[tid] = r;
            mrs[tid] = med[tid] * r;
        }
        const int ck = bid * 4 + w;                      // covers [0, 1280)
        const float4 v = *(const float4*)(mu + (size_t)ck * DDIM + lane * 4);
        u16x4 pk;
        pk[0] = f2bf(v.x); pk[1] = f2bf(v.y); pk[2] = f2bf(v.z); pk[3] = f2bf(v.w);
        *(u16x4*)(mubf + (size_t)ck * DDIM + lane * 4) = pk;
        float s = v.x * v.x + v.y * v.y + v.z * v.z + v.w * v.w;
#pragma unroll
        for (int off = 32; off > 0; off >>= 1) s += shfl_xor_f(s, off);
        if (lane == 0) {
            mu2[ck] = s;
            const float e = exp_temp[ck];
            const float t = 100.0f / (1.0f + __expf(-0.5f * e)) + 0.01f;
            rtau[ck] = 1.0f / t;
            ltau[ck] = logf(t);
            const int c = ck >> 6;
            const float thr = runb[c] * (0.5f / (float)KNUM);
            vldf[ck] = (runa[ck] > thr) ? 1.0f : 0.0f;
        }
    } else {
        const int b2 = bid - 320;
        if (tid < CNUM) h[tid] = 0;
        __syncthreads();
        for (int i = b2 * 256 + tid; i < N; i += NHB * 256)
            atomicAdd(&h[labels[i]], 1);
        __syncthreads();
        if (tid < CNUM) bc[b2 * CNUM + tid] = h[tid];
    }
}

// ---- K_B: counts, padded offsets, scatter bases, block->class map ----
__global__ void k_scan(const int* __restrict__ bc, int nb, int* __restrict__ cnt,
                       int* __restrict__ ps, int* __restrict__ sb,
                       int* __restrict__ blk2cls)
{
    const int t = threadIdx.x;
    if (t < CNUM) {
        int s = 0;
#pragma unroll 8
        for (int b = 0; b < nb; b++) s += bc[b * CNUM + t];
        cnt[t] = s;
    }
    __syncthreads();
    if (t == 0) {
        int run = 0;
        for (int c = 0; c < CNUM; c++) { ps[c] = run; run += (cnt[c] + 63) & ~63; }
        ps[CNUM] = run;
    }
    __syncthreads();
    if (t < CNUM) {
        int run = ps[t];
#pragma unroll 8
        for (int b = 0; b < nb; b++) { sb[b * CNUM + t] = run; run += bc[b * CNUM + t]; }
        const int b0 = ps[t] >> 6, b1 = ps[t + 1] >> 6;
        for (int b = b0; b < b1; b++) blk2cls[b] = t;
    }
}

// ---- K_C: scatter sample ids into class-sorted padded index array ----
__global__ void k_scatter(const int* __restrict__ labels, int N, const int* __restrict__ sb,
                          int* __restrict__ idx)
{
    __shared__ int cur[CNUM];
    const int tid = threadIdx.x;
    if (tid < CNUM) cur[tid] = sb[blockIdx.x * CNUM + tid];
    __syncthreads();
    for (int i = blockIdx.x * blockDim.x + tid; i < N; i += gridDim.x * blockDim.x) {
        const int c = labels[i];
        const int p = atomicAdd(&cur[c], 1);
        idx[p] = i;
    }
}

// ---- K_D: main — global_load_lds staging (fp32, swizzled src) -> MFMA -> softmax.
// ----      Barrier-free: each wave stages and reads only its own 16 rows. ----
__global__ __launch_bounds__(256, 4)
void k_main(const float* __restrict__ data, const unsigned short* __restrict__ mubf,
            const float* __restrict__ mrs, const float* __restrict__ rstd,
            const float* __restrict__ mu2, const float* __restrict__ rtau,
            const float* __restrict__ ltau, const float* __restrict__ vldf,
            const int* __restrict__ idx, const int* __restrict__ ps,
            const int* __restrict__ cnt, const int* __restrict__ blk2cls,
            float* __restrict__ wpart)
{
    __shared__ __align__(16) unsigned char Xs[64 * 512];  // fp32 half-rows [64][128 f32]
    const int tid = threadIdx.x, w = tid >> 6, lane = tid & 63;
    const int g = blockIdx.x;
    const int slot0 = g * 64;
    const int padtot = ps[CNUM];
    if (slot0 >= padtot) { if (lane == 0) wpart[g * 4 + w] = 0.f; return; }
    const int c = blk2cls[g];
    const int relast = ps[c] + cnt[c] - 1;               // last real slot (>= slot0)

    const int n16 = lane & 15, kg = lane >> 4;
    const int h2 = lane >> 5;                            // half-wave id
    const int m31 = 16 * (lane & 31);                    // byte chunk in half-row

    // per-lane sample ids for this wave's 8 row-pairs (row = 16w + 2*pr + h2)
    int nid[8];
#pragma unroll
    for (int pr = 0; pr < 8; ++pr) {
        const int slot = slot0 + 16 * w + 2 * pr + h2;
        nid[pr] = idx[min(slot, relast)];                // pads duplicate a real row
    }

    const unsigned short* __restrict__ mbase =
        mubf + ((size_t)c * KNUM + n16) * DDIM + 8 * kg;
    const int brow = 16 * w + n16;                       // this lane's sample row
    const int Sb = 32 * (n16 & 7) + 16 * ((n16 >> 3) & 1);   // read-side swizzle
    const unsigned char* __restrict__ xrd = Xs + brow * 512;

    f32x4 acc[4] = {};
    float q = 0.f;

#pragma unroll
    for (int p = 0; p < 2; ++p) {
        // ---- stage: 8 x global_load_lds, two half-rows per instruction ----
#pragma unroll
        for (int pr = 0; pr < 8; ++pr) {
            const int row = 16 * w + 2 * pr + h2;
            const int Sw = 32 * (row & 7) + 16 * ((row >> 3) & 1);
            const unsigned char* src =
                (const unsigned char*)(data + (size_t)nid[pr] * DDIM)
                + 512 * p + (m31 ^ Sw);                  // pre-swizzled global source
            void* dst = (void*)(Xs + (size_t)(16 * w + 2 * pr) * 512); // linear dest
            __builtin_amdgcn_global_load_lds(
                (const __attribute__((address_space(1))) void*)src,
                (__attribute__((address_space(3))) void*)dst, 16, 0, 0);
        }
        asm volatile("s_waitcnt vmcnt(0)" ::: "memory");

        // ---- per K-step: LDS fp32 -> normalize -> bf16 frag; mu frag; 4 MFMA ----
#pragma unroll
        for (int s = 0; s < 4; ++s) {
            const int b0 = 128 * s + 32 * kg;
            const float4 u0 = *(const float4*)(xrd + (b0 ^ Sb));
            const float4 u1 = *(const float4*)(xrd + ((b0 + 16) ^ Sb));
            const int d = 128 * p + 32 * s + 8 * kg;
            const float4 r0 = *(const float4*)(rstd + d);
            const float4 r1 = *(const float4*)(rstd + d + 4);
            const float4 m0 = *(const float4*)(mrs + d);
            const float4 m1 = *(const float4*)(mrs + d + 4);
            float a[8];
            a[0] = fmaf(u0.x, r0.x, -m0.x); a[1] = fmaf(u0.y, r0.y, -m0.y);
            a[2] = fmaf(u0.z, r0.z, -m0.z); a[3] = fmaf(u0.w, r0.w, -m0.w);
            a[4] = fmaf(u1.x, r1.x, -m1.x); a[5] = fmaf(u1.y, r1.y, -m1.y);
            a[6] = fmaf(u1.z, r1.z, -m1.z); a[7] = fmaf(u1.w, r1.w, -m1.w);
            union { short8 s8; __hip_bfloat162 b2[4]; } pk;
#pragma unroll
            for (int j = 0; j < 4; ++j) {
                q = fmaf(a[2 * j], a[2 * j], q);
                q = fmaf(a[2 * j + 1], a[2 * j + 1], q);
                pk.b2[j] = __float22bfloat162_rn(float2{a[2 * j], a[2 * j + 1]});
            }
            short8 af[4];
#pragma unroll
            for (int f = 0; f < 4; ++f)
                af[f] = *(const short8*)(mbase + f * 16 * DDIM + d - 8 * kg + 8 * kg);
#pragma unroll
            for (int f = 0; f < 4; ++f)
                acc[f] = __builtin_amdgcn_mfma_f32_16x16x32_bf16(af[f], pk.s8, acc[f], 0, 0, 0);
        }
    }
    // combine the 4 kg quarters of |x|^2 (same sample across kg)
    q += shfl_xor_f(q, 16);
    q += shfl_xor_f(q, 32);

    // ---- epilogue: lane holds 16 k-values (k = 16f + 4kg + r) of its sample ----
    const int ckb = c * KNUM;
    float simv[16], lpv[16];
    float mxv = -3.4e38f;
#pragma unroll
    for (int f = 0; f < 4; ++f) {
        const int kb = ckb + 16 * f + 4 * kg;
        const float4 m2v = *(const float4*)(mu2 + kb);
        const float4 rtv = *(const float4*)(rtau + kb);
        const float4 ltv = *(const float4*)(ltau + kb);
        const float4 vlv = *(const float4*)(vldf + kb);
#pragma unroll
        for (int r = 0; r < 4; ++r) {
            const float m2 = (&m2v.x)[r];
            const float d2 = fmaxf(fmaf(-2.0f, acc[f][r], q + m2), 0.f);
            const float dist = -6.25f * sqrtf(d2);       // 100/sqrt(256)
            const float sim = ((&vlv.x)[r] > 0.5f) ? dist : -1.0e12f;
            simv[4 * f + r] = sim;
            lpv[4 * f + r] = fmaf(sim, (&rtv.x)[r], -(&ltv.x)[r]);
            mxv = fmaxf(mxv, 0.5f * sim);
        }
    }
    mxv = fmaxf(mxv, shfl_xor_f(mxv, 16));
    mxv = fmaxf(mxv, shfl_xor_f(mxv, 32));
    float se = 0.f, sl = 0.f;
#pragma unroll
    for (int i = 0; i < 16; ++i) {
        const float e = __expf(fmaf(0.5f, simv[i], -mxv));
        se += e;
        sl = fmaf(e, lpv[i], sl);
    }
    se += shfl_xor_f(se, 16); se += shfl_xor_f(se, 32);
    sl += shfl_xor_f(sl, 16); sl += shfl_xor_f(sl, 32);
    const int slot = slot0 + brow;
    float res = (kg == 0 && slot <= relast) ? (-sl / se) : 0.f;
    res += shfl_xor_f(res, 1);
    res += shfl_xor_f(res, 2);
    res += shfl_xor_f(res, 4);
    res += shfl_xor_f(res, 8);
    if (lane == 0) wpart[g * 4 + w] = res;
}

// ---- K_E: deterministic per-class reduce -> loss ----
__global__ void k_final(const float* __restrict__ wpart, const int* __restrict__ ps,
                        const int* __restrict__ cnt, float* __restrict__ out)
{
    __shared__ float seg[CNUM];
    const int t = threadIdx.x;
    if (t < CNUM) {
        float s = 0.f;
        const int b0 = ps[t] >> 6, b1 = ps[t + 1] >> 6;
        for (int b = b0; b < b1; b++) {
            const float4 v = *(const float4*)(wpart + 4 * b);
            s += ((v.x + v.y) + (v.z + v.w));
        }
        seg[t] = s;
    }
    __syncthreads();
    if (t == 0) {
        float loss = 0.f;
        for (int c = 0; c < CNUM; c++) {
            const float cc = (float)cnt[c];
            if (cc > 0.f) loss += seg[c] / fmaxf(cc, 1.0f);
        }
        out[0] = loss;
    }
}

extern "C" void kernel_launch(void* const* d_in, const int* in_sizes, int n_in,
                              void* d_out, int out_size, void* d_ws, size_t ws_size,
                              hipStream_t stream)
{
    const float* data     = (const float*)d_in[0];
    const int*   labels   = (const int*)d_in[1];
    const float* mu       = (const float*)d_in[2];
    const float* exp_temp = (const float*)d_in[3];
    const float* med      = (const float*)d_in[4];
    const float* stdv     = (const float*)d_in[5];
    const float* runa     = (const float*)d_in[6];
    const float* runb     = (const float*)d_in[7];
    float* out = (float*)d_out;
    const int N = in_sizes[0] / DDIM;
    const int idx_slots = N + CNUM * 64;
    const int NB = (idx_slots + 63) / 64;

    char* w = (char*)d_ws;
    float* mu2  = (float*)w; w += (size_t)CNUM * KNUM * 4;
    float* rtau = (float*)w; w += (size_t)CNUM * KNUM * 4;
    float* ltau = (float*)w; w += (size_t)CNUM * KNUM * 4;
    float* vldf = (float*)w; w += (size_t)CNUM * KNUM * 4;
    float* rstd = (float*)w; w += (size_t)DDIM * 4;
    float* mrs  = (float*)w; w += (size_t)DDIM * 4;
    unsigned short* mubf = (unsigned short*)w; w += (size_t)CNUM * KNUM * DDIM * 2;
    int* bc  = (int*)w; w += (size_t)NHB * CNUM * 4;
    int* sb  = (int*)w; w += (size_t)NHB * CNUM * 4;
    int* cnt = (int*)w; w += 64 * 4;
    int* ps  = (int*)w; w += 64 * 4;
    int* idx = (int*)w; w += (size_t)idx_slots * 4;
    int* blk2cls = (int*)w; w += (size_t)NB * 4;
    float* wp = (float*)w; w += (size_t)NB * 4 * 4;

    k_setup<<<dim3(384), dim3(256), 0, stream>>>(
        mu, exp_temp, runa, runb, med, stdv, labels, N,
        mu2, rtau, ltau, vldf, rstd, mrs, mubf, bc);
    k_scan<<<dim3(1), dim3(64), 0, stream>>>(bc, NHB, cnt, ps, sb, blk2cls);
    k_scatter<<<dim3(NHB), dim3(256), 0, stream>>>(labels, N, sb, idx);
    k_main<<<dim3(NB), dim3(256), 0, stream>>>(
        data, mubf, mrs, rstd, mu2, rtau, ltau, vldf, idx, ps, cnt, blk2cls, wp);
    k_final<<<dim3(1), dim3(32), 0, stream>>>(wp, ps, cnt, out);
}